// Round 2
// baseline (822.669 us; speedup 1.0000x reference)
//
#include <hip/hip_runtime.h>

#define NN 100000
#define EE 1600000
#define K1 128
#define HH 64

// ---------------- setup kernels ----------------

__global__ void k_zero2(int* __restrict__ a, int* __restrict__ b, int n) {
    int i = blockIdx.x * 256 + threadIdx.x;
    if (i < n) { a[i] = 0; b[i] = 0; }
}

__global__ void k_hist(const int* __restrict__ ei, int* __restrict__ counts) {
    int e = blockIdx.x * 256 + threadIdx.x;
    if (e < EE) {
        int d = ei[EE + e];
        atomicAdd(&counts[d], 1);
    }
}

__global__ void k_scan_part(const int* __restrict__ counts, int* __restrict__ bsum, int n) {
    __shared__ int sm[256];
    int t = threadIdx.x;
    int base = blockIdx.x * 1024 + t * 4;
    int s = 0;
#pragma unroll
    for (int i = 0; i < 4; i++) { int idx = base + i; if (idx < n) s += counts[idx]; }
    sm[t] = s; __syncthreads();
    for (int off = 128; off > 0; off >>= 1) {
        if (t < off) sm[t] += sm[t + off];
        __syncthreads();
    }
    if (t == 0) bsum[blockIdx.x] = sm[0];
}

__global__ void k_scan_top(int* __restrict__ bsum, int nb) {
    if (threadIdx.x == 0) {
        int acc = 0;
        for (int b = 0; b < nb; b++) { int v = bsum[b]; bsum[b] = acc; acc += v; }
    }
}

__global__ void k_scan_final(const int* __restrict__ counts, const int* __restrict__ bsum,
                             int* __restrict__ offsets, int n) {
    __shared__ int sa[256], sb[256];
    int t = threadIdx.x;
    int base = blockIdx.x * 1024 + t * 4;
    int v[4]; int s = 0;
#pragma unroll
    for (int i = 0; i < 4; i++) { int idx = base + i; v[i] = (idx < n) ? counts[idx] : 0; s += v[i]; }
    sa[t] = s; __syncthreads();
    int* cur = sa; int* nxt = sb;
    for (int o = 1; o < 256; o <<= 1) {
        int val = cur[t];
        if (t >= o) val += cur[t - o];
        nxt[t] = val; __syncthreads();
        int* tmp = cur; cur = nxt; nxt = tmp;
    }
    int excl = cur[t] - s;
    int run = bsum[blockIdx.x] + excl;
#pragma unroll
    for (int i = 0; i < 4; i++) {
        int idx = base + i;
        if (idx < n) offsets[idx] = run;
        run += v[i];
    }
}

__global__ void k_dinv(const int* __restrict__ counts, float* __restrict__ dinv, int n) {
    int i = blockIdx.x * 256 + threadIdx.x;
    if (i < n) dinv[i] = rsqrtf((float)counts[i] + 1.0f);
}

__global__ void k_fill(const int* __restrict__ ei, const int* __restrict__ offsets,
                       int* __restrict__ cursor, const float* __restrict__ dinv,
                       int2* __restrict__ csr) {
    int e = blockIdx.x * 256 + threadIdx.x;
    if (e < EE) {
        int s = ei[e];
        int d = ei[EE + e];
        int p = offsets[d] + atomicAdd(&cursor[d], 1);
        float c = dinv[s] * dinv[d];
        csr[p] = make_int2(s, __float_as_int(c));
    }
}

// ---------------- GEMM: h[n][64] = x[n][K] @ W[K][64] ----------------
// wave = 8 rows, lane = output feature. W staged in LDS.

template <int K>
__global__ __launch_bounds__(256) void k_gemm(const float* __restrict__ x,
                                              const float* __restrict__ W,
                                              float* __restrict__ h) {
    __shared__ float Wl[K * 64];
    for (int i = threadIdx.x; i < K * 64; i += 256) Wl[i] = W[i];
    __syncthreads();
    int lane = threadIdx.x & 63;
    int wid = threadIdx.x >> 6;
    int base = (blockIdx.x * 4 + wid) * 8;   // 8 rows per wave, exact: N % 32 == 0
    float acc[8] = {0.f, 0.f, 0.f, 0.f, 0.f, 0.f, 0.f, 0.f};
    const float* xr = x + (size_t)base * K;
    for (int k = 0; k < K; k += 4) {
        float w0 = Wl[(k + 0) * 64 + lane];
        float w1 = Wl[(k + 1) * 64 + lane];
        float w2 = Wl[(k + 2) * 64 + lane];
        float w3 = Wl[(k + 3) * 64 + lane];
#pragma unroll
        for (int r = 0; r < 8; r++) {
            const float4 xv = *reinterpret_cast<const float4*>(xr + r * K + k);
            acc[r] = fmaf(xv.x, w0, acc[r]);
            acc[r] = fmaf(xv.y, w1, acc[r]);
            acc[r] = fmaf(xv.z, w2, acc[r]);
            acc[r] = fmaf(xv.w, w3, acc[r]);
        }
    }
    float* hp = h + (size_t)base * 64 + lane;
#pragma unroll
    for (int r = 0; r < 8; r++) hp[r * 64] = acc[r];
}

// ---------------- aggregation: out[n] = sum_e coef*h[src] + self*h[n] + b (+BN+ReLU) ----
// one wave per dst node, lane = feature. CSR gather, register accumulate.

template <bool BN>
__global__ __launch_bounds__(256) void k_agg(const float* __restrict__ h,
                                             const int2* __restrict__ csr,
                                             const int* __restrict__ offsets,
                                             const int* __restrict__ counts,
                                             const float* __restrict__ dinv,
                                             const float* __restrict__ bias,
                                             const float* __restrict__ g,
                                             const float* __restrict__ beta,
                                             const float* __restrict__ rm,
                                             const float* __restrict__ rv,
                                             float* __restrict__ out) {
    int node = (blockIdx.x * 256 + threadIdx.x) >> 6;
    int lane = threadIdx.x & 63;
    int start = offsets[node];
    int len = counts[node];
    float di = dinv[node];
    float acc = h[(size_t)node * 64 + lane] * (di * di);
    const int2* ep = csr + start;
    for (int i = 0; i < len; i++) {
        int2 e = ep[i];
        acc = fmaf(h[(size_t)e.x * 64 + lane], __int_as_float(e.y), acc);
    }
    acc += bias[lane];
    if (BN) {
        float sc = g[lane] * rsqrtf(rv[lane] + 1e-5f);
        acc = (acc - rm[lane]) * sc + beta[lane];
        acc = fmaxf(acc, 0.f);
    }
    out[(size_t)node * 64 + lane] = acc;
}

// ---------------- launch ----------------

extern "C" void kernel_launch(void* const* d_in, const int* in_sizes, int n_in,
                              void* d_out, int out_size, void* d_ws, size_t ws_size,
                              hipStream_t stream) {
    const float* x = (const float*)d_in[0];
    const int* ei = (const int*)d_in[1];        // int32 per harness contract, [2][E]
    const float* W1 = (const float*)d_in[2];
    const float* b1 = (const float*)d_in[3];
    const float* W2 = (const float*)d_in[4];
    const float* b2 = (const float*)d_in[5];
    const float* W3 = (const float*)d_in[6];
    const float* b3 = (const float*)d_in[7];
    const float* g1 = (const float*)d_in[8];
    const float* be1 = (const float*)d_in[9];
    const float* rm1 = (const float*)d_in[10];
    const float* rv1 = (const float*)d_in[11];
    const float* g2 = (const float*)d_in[12];
    const float* be2 = (const float*)d_in[13];
    const float* rm2 = (const float*)d_in[14];
    const float* rv2 = (const float*)d_in[15];
    float* out = (float*)d_out;

    char* ws = (char*)d_ws;
    size_t off = 0;
    auto alloc = [&](size_t bytes) -> void* {
        void* p = ws + off;
        off = (off + bytes + 255) & ~(size_t)255;
        return p;
    };
    int* counts = (int*)alloc((size_t)NN * 4);
    int* cursor = (int*)alloc((size_t)NN * 4);
    int* offsets = (int*)alloc((size_t)NN * 4);
    float* dinv = (float*)alloc((size_t)NN * 4);
    int* bsum = (int*)alloc(128 * 4);
    int2* csr = (int2*)alloc((size_t)EE * 8);
    float* bufA = (float*)alloc((size_t)NN * 64 * 4);
    float* bufB = (float*)alloc((size_t)NN * 64 * 4);

    const int SCAN_B = (NN + 1023) / 1024;  // 98

    k_zero2<<<(NN + 255) / 256, 256, 0, stream>>>(counts, cursor, NN);
    k_hist<<<EE / 256, 256, 0, stream>>>(ei, counts);
    k_scan_part<<<SCAN_B, 256, 0, stream>>>(counts, bsum, NN);
    k_scan_top<<<1, 64, 0, stream>>>(bsum, SCAN_B);
    k_scan_final<<<SCAN_B, 256, 0, stream>>>(counts, bsum, offsets, NN);
    k_dinv<<<(NN + 255) / 256, 256, 0, stream>>>(counts, dinv, NN);
    k_fill<<<EE / 256, 256, 0, stream>>>(ei, offsets, cursor, dinv, csr);

    // layer 1
    k_gemm<K1><<<NN / 32, 256, 0, stream>>>(x, W1, bufA);
    k_agg<true><<<NN * 64 / 256, 256, 0, stream>>>(bufA, csr, offsets, counts, dinv,
                                                   b1, g1, be1, rm1, rv1, bufB);
    // layer 2
    k_gemm<HH><<<NN / 32, 256, 0, stream>>>(bufB, W2, bufA);
    k_agg<true><<<NN * 64 / 256, 256, 0, stream>>>(bufA, csr, offsets, counts, dinv,
                                                   b2, g2, be2, rm2, rv2, bufB);
    // layer 3
    k_gemm<HH><<<NN / 32, 256, 0, stream>>>(bufB, W3, bufA);
    k_agg<false><<<NN * 64 / 256, 256, 0, stream>>>(bufA, csr, offsets, counts, dinv,
                                                    b3, b3, b3, b3, b3, out);
}

// Round 3
// 735.363 us; speedup vs baseline: 1.1187x; 1.1187x over previous
//
#include <hip/hip_runtime.h>

#define NN 100000
#define EE 1600000
#define K1 128
#define HH 64

// ---------------- setup kernels ----------------

__global__ void k_zero2(int* __restrict__ a, int* __restrict__ b, int n) {
    int i = blockIdx.x * 256 + threadIdx.x;
    if (i < n) { a[i] = 0; b[i] = 0; }
}

__global__ void k_hist(const int* __restrict__ ei, int* __restrict__ counts) {
    int e = blockIdx.x * 256 + threadIdx.x;
    if (e < EE) {
        int d = ei[EE + e];
        atomicAdd(&counts[d], 1);
    }
}

__global__ void k_scan_part(const int* __restrict__ counts, int* __restrict__ bsum, int n) {
    __shared__ int sm[256];
    int t = threadIdx.x;
    int base = blockIdx.x * 1024 + t * 4;
    int s = 0;
#pragma unroll
    for (int i = 0; i < 4; i++) { int idx = base + i; if (idx < n) s += counts[idx]; }
    sm[t] = s; __syncthreads();
    for (int off = 128; off > 0; off >>= 1) {
        if (t < off) sm[t] += sm[t + off];
        __syncthreads();
    }
    if (t == 0) bsum[blockIdx.x] = sm[0];
}

__global__ void k_scan_top(int* __restrict__ bsum, int nb) {
    if (threadIdx.x == 0) {
        int acc = 0;
        for (int b = 0; b < nb; b++) { int v = bsum[b]; bsum[b] = acc; acc += v; }
    }
}

__global__ void k_scan_final(const int* __restrict__ counts, const int* __restrict__ bsum,
                             int* __restrict__ offsets, int n) {
    __shared__ int sa[256], sb[256];
    int t = threadIdx.x;
    int base = blockIdx.x * 1024 + t * 4;
    int v[4]; int s = 0;
#pragma unroll
    for (int i = 0; i < 4; i++) { int idx = base + i; v[i] = (idx < n) ? counts[idx] : 0; s += v[i]; }
    sa[t] = s; __syncthreads();
    int* cur = sa; int* nxt = sb;
    for (int o = 1; o < 256; o <<= 1) {
        int val = cur[t];
        if (t >= o) val += cur[t - o];
        nxt[t] = val; __syncthreads();
        int* tmp = cur; cur = nxt; nxt = tmp;
    }
    int excl = cur[t] - s;
    int run = bsum[blockIdx.x] + excl;
#pragma unroll
    for (int i = 0; i < 4; i++) {
        int idx = base + i;
        if (idx < n) offsets[idx] = run;
        run += v[i];
    }
}

__global__ void k_dinv(const int* __restrict__ counts, float* __restrict__ dinv, int n) {
    int i = blockIdx.x * 256 + threadIdx.x;
    if (i < n) dinv[i] = rsqrtf((float)counts[i] + 1.0f);
}

__global__ void k_fill(const int* __restrict__ ei, const int* __restrict__ offsets,
                       int* __restrict__ cursor, const float* __restrict__ dinv,
                       int2* __restrict__ csr) {
    int e = blockIdx.x * 256 + threadIdx.x;
    if (e < EE) {
        int s = ei[e];
        int d = ei[EE + e];
        int p = offsets[d] + atomicAdd(&cursor[d], 1);
        float c = dinv[s] * dinv[d];
        csr[p] = make_int2(s, __float_as_int(c));
    }
}

// ---------------- GEMM: h[n][64] = x[n][K] @ W[K][64] ----------------

template <int K>
__global__ __launch_bounds__(256) void k_gemm(const float* __restrict__ x,
                                              const float* __restrict__ W,
                                              float* __restrict__ h) {
    __shared__ float Wl[K * 64];
    for (int i = threadIdx.x; i < K * 64; i += 256) Wl[i] = W[i];
    __syncthreads();
    int lane = threadIdx.x & 63;
    int wid = threadIdx.x >> 6;
    int base = (blockIdx.x * 4 + wid) * 8;   // 8 rows per wave, exact: N % 32 == 0
    float acc[8] = {0.f, 0.f, 0.f, 0.f, 0.f, 0.f, 0.f, 0.f};
    const float* xr = x + (size_t)base * K;
    for (int k = 0; k < K; k += 4) {
        float w0 = Wl[(k + 0) * 64 + lane];
        float w1 = Wl[(k + 1) * 64 + lane];
        float w2 = Wl[(k + 2) * 64 + lane];
        float w3 = Wl[(k + 3) * 64 + lane];
#pragma unroll
        for (int r = 0; r < 8; r++) {
            const float4 xv = *reinterpret_cast<const float4*>(xr + r * K + k);
            acc[r] = fmaf(xv.x, w0, acc[r]);
            acc[r] = fmaf(xv.y, w1, acc[r]);
            acc[r] = fmaf(xv.z, w2, acc[r]);
            acc[r] = fmaf(xv.w, w3, acc[r]);
        }
    }
    float* hp = h + (size_t)base * 64 + lane;
#pragma unroll
    for (int r = 0; r < 8; r++) hp[r * 64] = acc[r];
}

// ---------------- aggregation ----------------
// one wave per dst node, lane = feature. 8-deep batched gather for MLP:
// branchless tail (clamp index, zero coef) keeps all 8 loads legal & unrolled.

template <bool BN>
__global__ __launch_bounds__(256) void k_agg(const float* __restrict__ h,
                                             const int2* __restrict__ csr,
                                             const int* __restrict__ offsets,
                                             const int* __restrict__ counts,
                                             const float* __restrict__ dinv,
                                             const float* __restrict__ bias,
                                             const float* __restrict__ g,
                                             const float* __restrict__ beta,
                                             const float* __restrict__ rm,
                                             const float* __restrict__ rv,
                                             float* __restrict__ out) {
    int node = (blockIdx.x * 256 + threadIdx.x) >> 6;
    int lane = threadIdx.x & 63;
    int start = offsets[node];
    int len = counts[node];
    float di = dinv[node];
    float a0 = h[(size_t)node * 64 + lane] * (di * di);
    float a1 = 0.f, a2 = 0.f, a3 = 0.f;
    const int2* ep = csr + start;
    for (int i = 0; i < len; i += 8) {
        float v[8], c[8];
#pragma unroll
        for (int j = 0; j < 8; j++) {
            int idx = i + j;
            int2 e = ep[idx < len ? idx : len - 1];
            c[j] = (idx < len) ? __int_as_float(e.y) : 0.f;
            v[j] = h[(size_t)e.x * 64 + lane];
        }
        a0 = fmaf(v[0], c[0], a0);
        a1 = fmaf(v[1], c[1], a1);
        a2 = fmaf(v[2], c[2], a2);
        a3 = fmaf(v[3], c[3], a3);
        a0 = fmaf(v[4], c[4], a0);
        a1 = fmaf(v[5], c[5], a1);
        a2 = fmaf(v[6], c[6], a2);
        a3 = fmaf(v[7], c[7], a3);
    }
    float acc = (a0 + a1) + (a2 + a3);
    acc += bias[lane];
    if (BN) {
        float sc = g[lane] * rsqrtf(rv[lane] + 1e-5f);
        acc = (acc - rm[lane]) * sc + beta[lane];
        acc = fmaxf(acc, 0.f);
    }
    out[(size_t)node * 64 + lane] = acc;
}

// ---------------- launch ----------------

extern "C" void kernel_launch(void* const* d_in, const int* in_sizes, int n_in,
                              void* d_out, int out_size, void* d_ws, size_t ws_size,
                              hipStream_t stream) {
    const float* x = (const float*)d_in[0];
    const int* ei = (const int*)d_in[1];        // int32 per harness contract, [2][E]
    const float* W1 = (const float*)d_in[2];
    const float* b1 = (const float*)d_in[3];
    const float* W2 = (const float*)d_in[4];
    const float* b2 = (const float*)d_in[5];
    const float* W3 = (const float*)d_in[6];
    const float* b3 = (const float*)d_in[7];
    const float* g1 = (const float*)d_in[8];
    const float* be1 = (const float*)d_in[9];
    const float* rm1 = (const float*)d_in[10];
    const float* rv1 = (const float*)d_in[11];
    const float* g2 = (const float*)d_in[12];
    const float* be2 = (const float*)d_in[13];
    const float* rm2 = (const float*)d_in[14];
    const float* rv2 = (const float*)d_in[15];
    float* out = (float*)d_out;

    char* ws = (char*)d_ws;
    size_t off = 0;
    auto alloc = [&](size_t bytes) -> void* {
        void* p = ws + off;
        off = (off + bytes + 255) & ~(size_t)255;
        return p;
    };
    int* counts = (int*)alloc((size_t)NN * 4);
    int* cursor = (int*)alloc((size_t)NN * 4);
    int* offsets = (int*)alloc((size_t)NN * 4);
    float* dinv = (float*)alloc((size_t)NN * 4);
    int* bsum = (int*)alloc(128 * 4);
    int2* csr = (int2*)alloc((size_t)EE * 8);
    float* bufA = (float*)alloc((size_t)NN * 64 * 4);
    float* bufB = (float*)alloc((size_t)NN * 64 * 4);

    const int SCAN_B = (NN + 1023) / 1024;  // 98

    k_zero2<<<(NN + 255) / 256, 256, 0, stream>>>(counts, cursor, NN);
    k_hist<<<EE / 256, 256, 0, stream>>>(ei, counts);
    k_scan_part<<<SCAN_B, 256, 0, stream>>>(counts, bsum, NN);
    k_scan_top<<<1, 64, 0, stream>>>(bsum, SCAN_B);
    k_scan_final<<<SCAN_B, 256, 0, stream>>>(counts, bsum, offsets, NN);
    k_dinv<<<(NN + 255) / 256, 256, 0, stream>>>(counts, dinv, NN);
    k_fill<<<EE / 256, 256, 0, stream>>>(ei, offsets, cursor, dinv, csr);

    // layer 1
    k_gemm<K1><<<NN / 32, 256, 0, stream>>>(x, W1, bufA);
    k_agg<true><<<NN * 64 / 256, 256, 0, stream>>>(bufA, csr, offsets, counts, dinv,
                                                   b1, g1, be1, rm1, rv1, bufB);
    // layer 2
    k_gemm<HH><<<NN / 32, 256, 0, stream>>>(bufB, W2, bufA);
    k_agg<true><<<NN * 64 / 256, 256, 0, stream>>>(bufA, csr, offsets, counts, dinv,
                                                   b2, g2, be2, rm2, rv2, bufB);
    // layer 3
    k_gemm<HH><<<NN / 32, 256, 0, stream>>>(bufB, W3, bufA);
    k_agg<false><<<NN * 64 / 256, 256, 0, stream>>>(bufA, csr, offsets, counts, dinv,
                                                    b3, b3, b3, b3, b3, out);
}

// Round 4
// 615.129 us; speedup vs baseline: 1.3374x; 1.1955x over previous
//
#include <hip/hip_runtime.h>
#include <hip/hip_fp16.h>

#define NN 100000
#define EE 1600000
#define K1 128
#define HH 64

// ---------------- setup kernels ----------------

__global__ void k_zero2(int* __restrict__ a, int* __restrict__ b, int n) {
    int i = blockIdx.x * 256 + threadIdx.x;
    if (i < n) { a[i] = 0; b[i] = 0; }
}

__global__ void k_hist(const int* __restrict__ ei, int* __restrict__ counts) {
    int e = blockIdx.x * 256 + threadIdx.x;
    if (e < EE) {
        int d = ei[EE + e];
        atomicAdd(&counts[d], 1);
    }
}

__global__ void k_scan_part(const int* __restrict__ counts, int* __restrict__ bsum, int n) {
    __shared__ int sm[256];
    int t = threadIdx.x;
    int base = blockIdx.x * 1024 + t * 4;
    int s = 0;
#pragma unroll
    for (int i = 0; i < 4; i++) { int idx = base + i; if (idx < n) s += counts[idx]; }
    sm[t] = s; __syncthreads();
    for (int off = 128; off > 0; off >>= 1) {
        if (t < off) sm[t] += sm[t + off];
        __syncthreads();
    }
    if (t == 0) bsum[blockIdx.x] = sm[0];
}

__global__ void k_scan_top(int* __restrict__ bsum, int nb) {
    if (threadIdx.x == 0) {
        int acc = 0;
        for (int b = 0; b < nb; b++) { int v = bsum[b]; bsum[b] = acc; acc += v; }
    }
}

// scan + offsets + dinv fused
__global__ void k_scan_final(const int* __restrict__ counts, const int* __restrict__ bsum,
                             int* __restrict__ offsets, float* __restrict__ dinv, int n) {
    __shared__ int sa[256], sb[256];
    int t = threadIdx.x;
    int base = blockIdx.x * 1024 + t * 4;
    int v[4]; int s = 0;
#pragma unroll
    for (int i = 0; i < 4; i++) { int idx = base + i; v[i] = (idx < n) ? counts[idx] : 0; s += v[i]; }
    sa[t] = s; __syncthreads();
    int* cur = sa; int* nxt = sb;
    for (int o = 1; o < 256; o <<= 1) {
        int val = cur[t];
        if (t >= o) val += cur[t - o];
        nxt[t] = val; __syncthreads();
        int* tmp = cur; cur = nxt; nxt = tmp;
    }
    int excl = cur[t] - s;
    int run = bsum[blockIdx.x] + excl;
#pragma unroll
    for (int i = 0; i < 4; i++) {
        int idx = base + i;
        if (idx < n) {
            offsets[idx] = run;
            dinv[idx] = rsqrtf((float)v[i] + 1.0f);
        }
        run += v[i];
    }
}

__global__ void k_fill(const int* __restrict__ ei, const int* __restrict__ offsets,
                       int* __restrict__ cursor, const float* __restrict__ dinv,
                       int2* __restrict__ csr) {
    int e = blockIdx.x * 256 + threadIdx.x;
    if (e < EE) {
        int s = ei[e];
        int d = ei[EE + e];
        int p = offsets[d] + atomicAdd(&cursor[d], 1);
        float c = dinv[s] * dinv[d];
        csr[p] = make_int2(s, __float_as_int(c));
    }
}

// ---------------- GEMM: h[n][64] = x[n][K] @ W[K][64], fp16 output ----------------

template <int K>
__global__ __launch_bounds__(256) void k_gemm(const float* __restrict__ x,
                                              const float* __restrict__ W,
                                              __half* __restrict__ h) {
    __shared__ float Wl[K * 64];
    for (int i = threadIdx.x; i < K * 64; i += 256) Wl[i] = W[i];
    __syncthreads();
    int lane = threadIdx.x & 63;
    int wid = threadIdx.x >> 6;
    int base = (blockIdx.x * 4 + wid) * 8;   // 8 rows per wave, N % 32 == 0
    float acc[8] = {0.f, 0.f, 0.f, 0.f, 0.f, 0.f, 0.f, 0.f};
    const float* xr = x + (size_t)base * K;
    for (int k = 0; k < K; k += 4) {
        float w0 = Wl[(k + 0) * 64 + lane];
        float w1 = Wl[(k + 1) * 64 + lane];
        float w2 = Wl[(k + 2) * 64 + lane];
        float w3 = Wl[(k + 3) * 64 + lane];
#pragma unroll
        for (int r = 0; r < 8; r++) {
            const float4 xv = *reinterpret_cast<const float4*>(xr + r * K + k);
            acc[r] = fmaf(xv.x, w0, acc[r]);
            acc[r] = fmaf(xv.y, w1, acc[r]);
            acc[r] = fmaf(xv.z, w2, acc[r]);
            acc[r] = fmaf(xv.w, w3, acc[r]);
        }
    }
    __half* hp = h + (size_t)base * 64 + lane;
#pragma unroll
    for (int r = 0; r < 8; r++) hp[r * 64] = __float2half(acc[r]);
}

// ---------------- aggregation (fp16 h, paired-edge gather) ----------------
// wave = 1 dst node. lanes 0-31 handle even batch slots, 32-63 odd slots.
// lane loads one dword = 2 fp16 features of its slot's src row:
// per vmem instruction, TWO edges' 128B rows are fetched (256B, coalesced).
// Tail: index clamped, coef zeroed (clamped loads hit L1).

template <bool BN>
__global__ __launch_bounds__(256) void k_agg(const __half* __restrict__ h,
                                             const int2* __restrict__ csr,
                                             const int* __restrict__ offsets,
                                             const int* __restrict__ counts,
                                             const float* __restrict__ dinv,
                                             const float* __restrict__ bias,
                                             const float* __restrict__ g,
                                             const float* __restrict__ beta,
                                             const float* __restrict__ rm,
                                             const float* __restrict__ rv,
                                             float* __restrict__ out) {
    int node = (blockIdx.x * 256 + threadIdx.x) >> 6;
    int lane = threadIdx.x & 63;
    int j = lane & 31;       // dword index within row (features 2j, 2j+1)
    int hf = lane >> 5;      // 0: even slots, 1: odd slots
    int start = offsets[node];
    int len = counts[node];
    const int2* ep = csr + start;
    const unsigned int* hp = (const unsigned int*)h;

    float acc0 = 0.f, acc1 = 0.f;
    for (int i = 0; i < len; i += 16) {
        unsigned int dw[8];
        float cf[8];
#pragma unroll
        for (int b = 0; b < 8; b++) {
            int idx = i + 2 * b + hf;
            int cl = idx < len ? idx : len - 1;
            int2 e = ep[cl];
            cf[b] = (idx < len) ? __int_as_float(e.y) : 0.f;
            dw[b] = hp[(size_t)e.x * 32 + j];
        }
#pragma unroll
        for (int b = 0; b < 8; b++) {
            __half2 h2 = *reinterpret_cast<const __half2*>(&dw[b]);
            float2 hv = __half22float2(h2);
            acc0 = fmaf(hv.x, cf[b], acc0);
            acc1 = fmaf(hv.y, cf[b], acc1);
        }
    }
    // combine even-slot and odd-slot partials across wave halves
    acc0 += __shfl_xor(acc0, 32);
    acc1 += __shfl_xor(acc1, 32);

    // self term
    unsigned int sdw = hp[(size_t)node * 32 + j];
    __half2 s2 = *reinterpret_cast<const __half2*>(&sdw);
    float2 sv = __half22float2(s2);
    float di = dinv[node];
    float d2 = di * di;

    int fv = 2 * j + hf;                       // feature this lane stores
    float acc = (hf == 0) ? acc0 : acc1;
    float selfv = (hf == 0) ? sv.x : sv.y;
    acc = fmaf(selfv, d2, acc) + bias[fv];
    if (BN) {
        float sc = g[fv] * rsqrtf(rv[fv] + 1e-5f);
        acc = (acc - rm[fv]) * sc + beta[fv];
        acc = fmaxf(acc, 0.f);
    }
    out[(size_t)node * 64 + fv] = acc;
}

// ---------------- launch ----------------

extern "C" void kernel_launch(void* const* d_in, const int* in_sizes, int n_in,
                              void* d_out, int out_size, void* d_ws, size_t ws_size,
                              hipStream_t stream) {
    const float* x = (const float*)d_in[0];
    const int* ei = (const int*)d_in[1];        // int32 per harness contract, [2][E]
    const float* W1 = (const float*)d_in[2];
    const float* b1 = (const float*)d_in[3];
    const float* W2 = (const float*)d_in[4];
    const float* b2 = (const float*)d_in[5];
    const float* W3 = (const float*)d_in[6];
    const float* b3 = (const float*)d_in[7];
    const float* g1 = (const float*)d_in[8];
    const float* be1 = (const float*)d_in[9];
    const float* rm1 = (const float*)d_in[10];
    const float* rv1 = (const float*)d_in[11];
    const float* g2 = (const float*)d_in[12];
    const float* be2 = (const float*)d_in[13];
    const float* rm2 = (const float*)d_in[14];
    const float* rv2 = (const float*)d_in[15];
    float* out = (float*)d_out;

    char* ws = (char*)d_ws;
    size_t off = 0;
    auto alloc = [&](size_t bytes) -> void* {
        void* p = ws + off;
        off = (off + bytes + 255) & ~(size_t)255;
        return p;
    };
    int* counts = (int*)alloc((size_t)NN * 4);
    int* cursor = (int*)alloc((size_t)NN * 4);
    int* offsets = (int*)alloc((size_t)NN * 4);
    float* dinv = (float*)alloc((size_t)NN * 4);
    int* bsum = (int*)alloc(128 * 4);
    int2* csr = (int2*)alloc((size_t)EE * 8);
    __half* h16 = (__half*)alloc((size_t)NN * 64 * 2);
    float* ybuf = (float*)alloc((size_t)NN * 64 * 4);

    const int SCAN_B = (NN + 1023) / 1024;  // 98

    k_zero2<<<(NN + 255) / 256, 256, 0, stream>>>(counts, cursor, NN);
    k_hist<<<EE / 256, 256, 0, stream>>>(ei, counts);
    k_scan_part<<<SCAN_B, 256, 0, stream>>>(counts, bsum, NN);
    k_scan_top<<<1, 64, 0, stream>>>(bsum, SCAN_B);
    k_scan_final<<<SCAN_B, 256, 0, stream>>>(counts, bsum, offsets, dinv, NN);
    k_fill<<<EE / 256, 256, 0, stream>>>(ei, offsets, cursor, dinv, csr);

    // layer 1
    k_gemm<K1><<<NN / 32, 256, 0, stream>>>(x, W1, h16);
    k_agg<true><<<NN * 64 / 256, 256, 0, stream>>>(h16, csr, offsets, counts, dinv,
                                                   b1, g1, be1, rm1, rv1, ybuf);
    // layer 2
    k_gemm<HH><<<NN / 32, 256, 0, stream>>>(ybuf, W2, h16);
    k_agg<true><<<NN * 64 / 256, 256, 0, stream>>>(h16, csr, offsets, counts, dinv,
                                                   b2, g2, be2, rm2, rv2, ybuf);
    // layer 3
    k_gemm<HH><<<NN / 32, 256, 0, stream>>>(ybuf, W3, h16);
    k_agg<false><<<NN * 64 / 256, 256, 0, stream>>>(h16, csr, offsets, counts, dinv,
                                                    b3, b3, b3, b3, b3, out);
}

// Round 5
// 509.923 us; speedup vs baseline: 1.6133x; 1.2063x over previous
//
#include <hip/hip_runtime.h>
#include <hip/hip_fp16.h>

#define NN 100000
#define EE 1600000
#define K1 128
#define HH 64

// ---------------- setup kernels ----------------

__global__ void k_zero2(int* __restrict__ a, int* __restrict__ b, int n) {
    int i = blockIdx.x * 256 + threadIdx.x;
    if (i < n) { a[i] = 0; b[i] = 0; }
}

__global__ void k_hist(const int* __restrict__ ei, int* __restrict__ counts) {
    int e = blockIdx.x * 256 + threadIdx.x;
    if (e < EE) {
        int d = ei[EE + e];
        atomicAdd(&counts[d], 1);
    }
}

__global__ void k_scan_part(const int* __restrict__ counts, int* __restrict__ bsum, int n) {
    __shared__ int sm[256];
    int t = threadIdx.x;
    int base = blockIdx.x * 1024 + t * 4;
    int s = 0;
#pragma unroll
    for (int i = 0; i < 4; i++) { int idx = base + i; if (idx < n) s += counts[idx]; }
    sm[t] = s; __syncthreads();
    for (int off = 128; off > 0; off >>= 1) {
        if (t < off) sm[t] += sm[t + off];
        __syncthreads();
    }
    if (t == 0) bsum[blockIdx.x] = sm[0];
}

__global__ void k_scan_top(int* __restrict__ bsum, int nb) {
    if (threadIdx.x == 0) {
        int acc = 0;
        for (int b = 0; b < nb; b++) { int v = bsum[b]; bsum[b] = acc; acc += v; }
    }
}

// scan + offsets + dinv fused
__global__ void k_scan_final(const int* __restrict__ counts, const int* __restrict__ bsum,
                             int* __restrict__ offsets, float* __restrict__ dinv, int n) {
    __shared__ int sa[256], sb[256];
    int t = threadIdx.x;
    int base = blockIdx.x * 1024 + t * 4;
    int v[4]; int s = 0;
#pragma unroll
    for (int i = 0; i < 4; i++) { int idx = base + i; v[i] = (idx < n) ? counts[idx] : 0; s += v[i]; }
    sa[t] = s; __syncthreads();
    int* cur = sa; int* nxt = sb;
    for (int o = 1; o < 256; o <<= 1) {
        int val = cur[t];
        if (t >= o) val += cur[t - o];
        nxt[t] = val; __syncthreads();
        int* tmp = cur; cur = nxt; nxt = tmp;
    }
    int excl = cur[t] - s;
    int run = bsum[blockIdx.x] + excl;
#pragma unroll
    for (int i = 0; i < 4; i++) {
        int idx = base + i;
        if (idx < n) {
            offsets[idx] = run;
            dinv[idx] = rsqrtf((float)v[i] + 1.0f);
        }
        run += v[i];
    }
}

__global__ void k_fill(const int* __restrict__ ei, const int* __restrict__ offsets,
                       int* __restrict__ cursor, const float* __restrict__ dinv,
                       int2* __restrict__ csr) {
    int e = blockIdx.x * 256 + threadIdx.x;
    if (e < EE) {
        int s = ei[e];
        int d = ei[EE + e];
        int p = offsets[d] + atomicAdd(&cursor[d], 1);
        float c = dinv[s] * dinv[d];
        csr[p] = make_int2(s, __float_as_int(c));
    }
}

// ---------------- GEMM: h[n][64] = x[n][K] @ W[K][64], fp16 output ----------------
// Both operands staged in LDS. Inner loop: W via stride-1 ds_read (2-way, free),
// x via wave-uniform ds_read_b128 broadcast (free). TM/4 rows per wave.

template <int K, int TM>
__global__ __launch_bounds__(256) void k_gemm(const float* __restrict__ x,
                                              const float* __restrict__ W,
                                              __half* __restrict__ h) {
    __shared__ float Wl[K * 64];
    __shared__ float xs[TM * K];
    int t = threadIdx.x;
    int base = blockIdx.x * TM;
    // stage W (K*16 float4s, linear copy)
    for (int i = t; i < K * 16; i += 256)
        reinterpret_cast<float4*>(Wl)[i] = reinterpret_cast<const float4*>(W)[i];
    // stage x tile rows [base, base+TM) — linear row-major copy, coalesced
    {
        const int NF4 = TM * K / 4;
        const int RF4 = K / 4;  // float4 per row
        for (int i = t; i < NF4; i += 256) {
            int r = i / RF4, c = i - r * RF4;
            int gr = base + r; if (gr >= NN) gr = NN - 1;
            reinterpret_cast<float4*>(xs)[i] =
                reinterpret_cast<const float4*>(x + (size_t)gr * K)[c];
        }
    }
    __syncthreads();

    int lane = t & 63;
    int wid = t >> 6;
    const int RW = TM / 4;          // rows per wave
    int r0 = wid * RW;
    float acc[RW];
#pragma unroll
    for (int r = 0; r < RW; r++) acc[r] = 0.f;

    for (int k = 0; k < K; k += 4) {
        float w0 = Wl[(k + 0) * 64 + lane];
        float w1 = Wl[(k + 1) * 64 + lane];
        float w2 = Wl[(k + 2) * 64 + lane];
        float w3 = Wl[(k + 3) * 64 + lane];
#pragma unroll
        for (int r = 0; r < RW; r++) {
            const float4 xv = *reinterpret_cast<const float4*>(&xs[(r0 + r) * K + k]);
            acc[r] = fmaf(xv.x, w0, acc[r]);
            acc[r] = fmaf(xv.y, w1, acc[r]);
            acc[r] = fmaf(xv.z, w2, acc[r]);
            acc[r] = fmaf(xv.w, w3, acc[r]);
        }
    }
    __half* hp = h + ((size_t)base + r0) * 64 + lane;
#pragma unroll
    for (int r = 0; r < RW; r++)
        if (base + r0 + r < NN) hp[r * 64] = __float2half(acc[r]);
}

// ---------------- aggregation (fp16 h, paired-edge gather) ----------------

template <bool BN>
__global__ __launch_bounds__(256) void k_agg(const __half* __restrict__ h,
                                             const int2* __restrict__ csr,
                                             const int* __restrict__ offsets,
                                             const int* __restrict__ counts,
                                             const float* __restrict__ dinv,
                                             const float* __restrict__ bias,
                                             const float* __restrict__ g,
                                             const float* __restrict__ beta,
                                             const float* __restrict__ rm,
                                             const float* __restrict__ rv,
                                             float* __restrict__ out) {
    int node = (blockIdx.x * 256 + threadIdx.x) >> 6;
    int lane = threadIdx.x & 63;
    int j = lane & 31;       // dword index within row (features 2j, 2j+1)
    int hf = lane >> 5;      // 0: even slots, 1: odd slots
    int start = offsets[node];
    int len = counts[node];
    const int2* ep = csr + start;
    const unsigned int* hp = (const unsigned int*)h;

    float acc0 = 0.f, acc1 = 0.f;
    for (int i = 0; i < len; i += 16) {
        unsigned int dw[8];
        float cf[8];
#pragma unroll
        for (int b = 0; b < 8; b++) {
            int idx = i + 2 * b + hf;
            int cl = idx < len ? idx : len - 1;
            int2 e = ep[cl];
            cf[b] = (idx < len) ? __int_as_float(e.y) : 0.f;
            dw[b] = hp[(size_t)e.x * 32 + j];
        }
#pragma unroll
        for (int b = 0; b < 8; b++) {
            __half2 h2 = *reinterpret_cast<const __half2*>(&dw[b]);
            float2 hv = __half22float2(h2);
            acc0 = fmaf(hv.x, cf[b], acc0);
            acc1 = fmaf(hv.y, cf[b], acc1);
        }
    }
    acc0 += __shfl_xor(acc0, 32);
    acc1 += __shfl_xor(acc1, 32);

    unsigned int sdw = hp[(size_t)node * 32 + j];
    __half2 s2 = *reinterpret_cast<const __half2*>(&sdw);
    float2 sv = __half22float2(s2);
    float di = dinv[node];
    float d2 = di * di;

    int fv = 2 * j + hf;
    float acc = (hf == 0) ? acc0 : acc1;
    float selfv = (hf == 0) ? sv.x : sv.y;
    acc = fmaf(selfv, d2, acc) + bias[fv];
    if (BN) {
        float sc = g[fv] * rsqrtf(rv[fv] + 1e-5f);
        acc = (acc - rm[fv]) * sc + beta[fv];
        acc = fmaxf(acc, 0.f);
    }
    out[(size_t)node * 64 + fv] = acc;
}

// ---------------- launch ----------------

extern "C" void kernel_launch(void* const* d_in, const int* in_sizes, int n_in,
                              void* d_out, int out_size, void* d_ws, size_t ws_size,
                              hipStream_t stream) {
    const float* x = (const float*)d_in[0];
    const int* ei = (const int*)d_in[1];        // int32 per harness contract, [2][E]
    const float* W1 = (const float*)d_in[2];
    const float* b1 = (const float*)d_in[3];
    const float* W2 = (const float*)d_in[4];
    const float* b2 = (const float*)d_in[5];
    const float* W3 = (const float*)d_in[6];
    const float* b3 = (const float*)d_in[7];
    const float* g1 = (const float*)d_in[8];
    const float* be1 = (const float*)d_in[9];
    const float* rm1 = (const float*)d_in[10];
    const float* rv1 = (const float*)d_in[11];
    const float* g2 = (const float*)d_in[12];
    const float* be2 = (const float*)d_in[13];
    const float* rm2 = (const float*)d_in[14];
    const float* rv2 = (const float*)d_in[15];
    float* out = (float*)d_out;

    char* ws = (char*)d_ws;
    size_t off = 0;
    auto alloc = [&](size_t bytes) -> void* {
        void* p = ws + off;
        off = (off + bytes + 255) & ~(size_t)255;
        return p;
    };
    int* counts = (int*)alloc((size_t)NN * 4);
    int* cursor = (int*)alloc((size_t)NN * 4);
    int* offsets = (int*)alloc((size_t)NN * 4);
    float* dinv = (float*)alloc((size_t)NN * 4);
    int* bsum = (int*)alloc(128 * 4);
    int2* csr = (int2*)alloc((size_t)EE * 8);
    __half* h16 = (__half*)alloc((size_t)NN * 64 * 2);
    float* ybuf = (float*)alloc((size_t)NN * 64 * 4);

    const int SCAN_B = (NN + 1023) / 1024;  // 98

    k_zero2<<<(NN + 255) / 256, 256, 0, stream>>>(counts, cursor, NN);
    k_hist<<<EE / 256, 256, 0, stream>>>(ei, counts);
    k_scan_part<<<SCAN_B, 256, 0, stream>>>(counts, bsum, NN);
    k_scan_top<<<1, 64, 0, stream>>>(bsum, SCAN_B);
    k_scan_final<<<SCAN_B, 256, 0, stream>>>(counts, bsum, offsets, dinv, NN);
    k_fill<<<EE / 256, 256, 0, stream>>>(ei, offsets, cursor, dinv, csr);

    // layer 1: K=128, TILE_M=32 (LDS 48KB), grid exact 3125
    k_gemm<K1, 32><<<NN / 32, 256, 0, stream>>>(x, W1, h16);
    k_agg<true><<<NN * 64 / 256, 256, 0, stream>>>(h16, csr, offsets, counts, dinv,
                                                   b1, g1, be1, rm1, rv1, ybuf);
    // layer 2: K=64, TILE_M=64 (LDS 32KB)
    k_gemm<HH, 64><<<(NN + 63) / 64, 256, 0, stream>>>(ybuf, W2, h16);
    k_agg<true><<<NN * 64 / 256, 256, 0, stream>>>(h16, csr, offsets, counts, dinv,
                                                   b2, g2, be2, rm2, rv2, ybuf);
    // layer 3
    k_gemm<HH, 64><<<(NN + 63) / 64, 256, 0, stream>>>(ybuf, W3, h16);
    k_agg<false><<<NN * 64 / 256, 256, 0, stream>>>(h16, csr, offsets, counts, dinv,
                                                    b3, b3, b3, b3, b3, out);
}

// Round 6
// 444.901 us; speedup vs baseline: 1.8491x; 1.1462x over previous
//
#include <hip/hip_runtime.h>
#include <hip/hip_fp16.h>

#define NN 100000
#define EE 1600000
#define K1 128
#define HH 64

// ---------------- setup kernels ----------------

__global__ void k_zero2(int* __restrict__ a, int* __restrict__ b, int n) {
    int i = blockIdx.x * 256 + threadIdx.x;
    if (i < n) { a[i] = 0; b[i] = 0; }
}

__global__ void k_hist(const int* __restrict__ ei, int* __restrict__ counts) {
    int e = blockIdx.x * 256 + threadIdx.x;
    if (e < EE) {
        int d = ei[EE + e];
        atomicAdd(&counts[d], 1);
    }
}

__global__ void k_scan_part(const int* __restrict__ counts, int* __restrict__ bsum, int n) {
    __shared__ int sm[256];
    int t = threadIdx.x;
    int base = blockIdx.x * 1024 + t * 4;
    int s = 0;
#pragma unroll
    for (int i = 0; i < 4; i++) { int idx = base + i; if (idx < n) s += counts[idx]; }
    sm[t] = s; __syncthreads();
    for (int off = 128; off > 0; off >>= 1) {
        if (t < off) sm[t] += sm[t + off];
        __syncthreads();
    }
    if (t == 0) bsum[blockIdx.x] = sm[0];
}

__global__ void k_scan_top(int* __restrict__ bsum, int nb) {
    if (threadIdx.x == 0) {
        int acc = 0;
        for (int b = 0; b < nb; b++) { int v = bsum[b]; bsum[b] = acc; acc += v; }
    }
}

// scan + offsets + dinv fused
__global__ void k_scan_final(const int* __restrict__ counts, const int* __restrict__ bsum,
                             int* __restrict__ offsets, float* __restrict__ dinv, int n) {
    __shared__ int sa[256], sb[256];
    int t = threadIdx.x;
    int base = blockIdx.x * 1024 + t * 4;
    int v[4]; int s = 0;
#pragma unroll
    for (int i = 0; i < 4; i++) { int idx = base + i; v[i] = (idx < n) ? counts[idx] : 0; s += v[i]; }
    sa[t] = s; __syncthreads();
    int* cur = sa; int* nxt = sb;
    for (int o = 1; o < 256; o <<= 1) {
        int val = cur[t];
        if (t >= o) val += cur[t - o];
        nxt[t] = val; __syncthreads();
        int* tmp = cur; cur = nxt; nxt = tmp;
    }
    int excl = cur[t] - s;
    int run = bsum[blockIdx.x] + excl;
#pragma unroll
    for (int i = 0; i < 4; i++) {
        int idx = base + i;
        if (idx < n) {
            offsets[idx] = run;
            dinv[idx] = rsqrtf((float)v[i] + 1.0f);
        }
        run += v[i];
    }
}

__global__ void k_fill(const int* __restrict__ ei, const int* __restrict__ offsets,
                       int* __restrict__ cursor, const float* __restrict__ dinv,
                       int2* __restrict__ csr) {
    int e = blockIdx.x * 256 + threadIdx.x;
    if (e < EE) {
        int s = ei[e];
        int d = ei[EE + e];
        int p = offsets[d] + atomicAdd(&cursor[d], 1);
        float c = dinv[s] * dinv[d];
        csr[p] = make_int2(s, __float_as_int(c));
    }
}

// ---------------- GEMM: h[n][64] = x[n][K] @ W[K][64], fp16 output ----------------
// Both operands in LDS; fp16 input converted to fp32 during staging so the
// inner loop stays float4 ds_reads + FMA.

template <int K, int TM, bool INH>
__global__ __launch_bounds__(256) void k_gemm(const void* __restrict__ xin,
                                              const float* __restrict__ W,
                                              __half* __restrict__ h) {
    __shared__ float Wl[K * 64];
    __shared__ float xs[TM * K];
    int t = threadIdx.x;
    int base = blockIdx.x * TM;
    for (int i = t; i < K * 16; i += 256)
        reinterpret_cast<float4*>(Wl)[i] = reinterpret_cast<const float4*>(W)[i];
    {
        const int NF4 = TM * K / 4;
        const int RF4 = K / 4;  // float4 (or uint2=4 halves) per row
        for (int i = t; i < NF4; i += 256) {
            int r = i / RF4, c = i - r * RF4;
            int gr = base + r; if (gr >= NN) gr = NN - 1;
            float4 v;
            if (INH) {
                uint2 u = reinterpret_cast<const uint2*>(xin)[(size_t)gr * RF4 + c];
                const __half2* hh = reinterpret_cast<const __half2*>(&u);
                float2 f01 = __half22float2(hh[0]);
                float2 f23 = __half22float2(hh[1]);
                v = make_float4(f01.x, f01.y, f23.x, f23.y);
            } else {
                v = reinterpret_cast<const float4*>(xin)[(size_t)gr * RF4 + c];
            }
            reinterpret_cast<float4*>(xs)[i] = v;
        }
    }
    __syncthreads();

    int lane = t & 63;
    int wid = t >> 6;
    const int RW = TM / 4;          // rows per wave
    int r0 = wid * RW;
    float acc[RW];
#pragma unroll
    for (int r = 0; r < RW; r++) acc[r] = 0.f;

    for (int k = 0; k < K; k += 4) {
        float w0 = Wl[(k + 0) * 64 + lane];
        float w1 = Wl[(k + 1) * 64 + lane];
        float w2 = Wl[(k + 2) * 64 + lane];
        float w3 = Wl[(k + 3) * 64 + lane];
#pragma unroll
        for (int r = 0; r < RW; r++) {
            const float4 xv = *reinterpret_cast<const float4*>(&xs[(r0 + r) * K + k]);
            acc[r] = fmaf(xv.x, w0, acc[r]);
            acc[r] = fmaf(xv.y, w1, acc[r]);
            acc[r] = fmaf(xv.z, w2, acc[r]);
            acc[r] = fmaf(xv.w, w3, acc[r]);
        }
    }
    __half* hp = h + ((size_t)base + r0) * 64 + lane;
#pragma unroll
    for (int r = 0; r < RW; r++)
        if (base + r0 + r < NN) hp[r * 64] = __float2half(acc[r]);
}

// ---------------- aggregation (fp16 h, quarter-wave gather) ----------------
// wave = 1 dst node. quarter q (16 lanes) owns edge slots; lane p loads
// uint2 = 4 fp16 feats (4p..4p+3): one vmem instruction fetches FOUR edges'
// 128B rows. csr read via nontemporal load (protect h in L2). Cross-quarter
// combine: 2 shfl_xor pairs; 16-lane float4 epilogue.

template <bool BN, bool OUTH>
__global__ __launch_bounds__(256) void k_agg(const __half* __restrict__ h,
                                             const int2* __restrict__ csr,
                                             const int* __restrict__ offsets,
                                             const int* __restrict__ counts,
                                             const float* __restrict__ dinv,
                                             const float* __restrict__ bias,
                                             const float* __restrict__ g,
                                             const float* __restrict__ beta,
                                             const float* __restrict__ rm,
                                             const float* __restrict__ rv,
                                             void* __restrict__ outp) {
    int node = (blockIdx.x * 256 + threadIdx.x) >> 6;
    int lane = threadIdx.x & 63;
    int q = lane >> 4;       // quarter: edge slot group
    int p = lane & 15;       // uint2 index within row (feats 4p..4p+3)
    int start = offsets[node];
    int len = counts[node];
    const long long* ep = reinterpret_cast<const long long*>(csr + start);
    const uint2* hp = reinterpret_cast<const uint2*>(h);

    float a0 = 0.f, a1 = 0.f, a2 = 0.f, a3 = 0.f;
    for (int i = 0; i < len; i += 16) {
        uint2 dv[4]; float cf[4];
#pragma unroll
        for (int s = 0; s < 4; s++) {
            int slot = i + 4 * q + s;
            int cl = slot < len ? slot : len - 1;
            long long ev = __builtin_nontemporal_load(ep + cl);
            int srcn = (int)ev;
            cf[s] = (slot < len) ? __int_as_float((int)(ev >> 32)) : 0.f;
            dv[s] = hp[(size_t)srcn * 16 + p];
        }
#pragma unroll
        for (int s = 0; s < 4; s++) {
            const __half2* hh = reinterpret_cast<const __half2*>(&dv[s]);
            float2 f01 = __half22float2(hh[0]);
            float2 f23 = __half22float2(hh[1]);
            a0 = fmaf(f01.x, cf[s], a0);
            a1 = fmaf(f01.y, cf[s], a1);
            a2 = fmaf(f23.x, cf[s], a2);
            a3 = fmaf(f23.y, cf[s], a3);
        }
    }
    a0 += __shfl_xor(a0, 16); a0 += __shfl_xor(a0, 32);
    a1 += __shfl_xor(a1, 16); a1 += __shfl_xor(a1, 32);
    a2 += __shfl_xor(a2, 16); a2 += __shfl_xor(a2, 32);
    a3 += __shfl_xor(a3, 16); a3 += __shfl_xor(a3, 32);

    if (q == 0) {
        uint2 sv = hp[(size_t)node * 16 + p];
        const __half2* sh = reinterpret_cast<const __half2*>(&sv);
        float2 s01 = __half22float2(sh[0]);
        float2 s23 = __half22float2(sh[1]);
        float di = dinv[node];
        float d2 = di * di;
        float4 bi = reinterpret_cast<const float4*>(bias)[p];
        float r0 = fmaf(s01.x, d2, a0) + bi.x;
        float r1 = fmaf(s01.y, d2, a1) + bi.y;
        float r2 = fmaf(s23.x, d2, a2) + bi.z;
        float r3 = fmaf(s23.y, d2, a3) + bi.w;
        if (BN) {
            float4 gv = reinterpret_cast<const float4*>(g)[p];
            float4 bv = reinterpret_cast<const float4*>(beta)[p];
            float4 mv = reinterpret_cast<const float4*>(rm)[p];
            float4 vv = reinterpret_cast<const float4*>(rv)[p];
            r0 = fmaxf(fmaf(r0 - mv.x, gv.x * rsqrtf(vv.x + 1e-5f), bv.x), 0.f);
            r1 = fmaxf(fmaf(r1 - mv.y, gv.y * rsqrtf(vv.y + 1e-5f), bv.y), 0.f);
            r2 = fmaxf(fmaf(r2 - mv.z, gv.z * rsqrtf(vv.z + 1e-5f), bv.z), 0.f);
            r3 = fmaxf(fmaf(r3 - mv.w, gv.w * rsqrtf(vv.w + 1e-5f), bv.w), 0.f);
        }
        if (OUTH) {
            __half2 o01, o23;
            o01.x = __float2half_rn(r0); o01.y = __float2half_rn(r1);
            o23.x = __float2half_rn(r2); o23.y = __float2half_rn(r3);
            uint2 o;
            o.x = *reinterpret_cast<unsigned*>(&o01);
            o.y = *reinterpret_cast<unsigned*>(&o23);
            reinterpret_cast<uint2*>(outp)[(size_t)node * 16 + p] = o;
        } else {
            float4 o = make_float4(r0, r1, r2, r3);
            reinterpret_cast<float4*>(outp)[(size_t)node * 16 + p] = o;
        }
    }
}

// ---------------- launch ----------------

extern "C" void kernel_launch(void* const* d_in, const int* in_sizes, int n_in,
                              void* d_out, int out_size, void* d_ws, size_t ws_size,
                              hipStream_t stream) {
    const float* x = (const float*)d_in[0];
    const int* ei = (const int*)d_in[1];        // int32 per harness contract, [2][E]
    const float* W1 = (const float*)d_in[2];
    const float* b1 = (const float*)d_in[3];
    const float* W2 = (const float*)d_in[4];
    const float* b2 = (const float*)d_in[5];
    const float* W3 = (const float*)d_in[6];
    const float* b3 = (const float*)d_in[7];
    const float* g1 = (const float*)d_in[8];
    const float* be1 = (const float*)d_in[9];
    const float* rm1 = (const float*)d_in[10];
    const float* rv1 = (const float*)d_in[11];
    const float* g2 = (const float*)d_in[12];
    const float* be2 = (const float*)d_in[13];
    const float* rm2 = (const float*)d_in[14];
    const float* rv2 = (const float*)d_in[15];
    float* out = (float*)d_out;

    char* ws = (char*)d_ws;
    size_t off = 0;
    auto alloc = [&](size_t bytes) -> void* {
        void* p = ws + off;
        off = (off + bytes + 255) & ~(size_t)255;
        return p;
    };
    int* counts = (int*)alloc((size_t)NN * 4);
    int* cursor = (int*)alloc((size_t)NN * 4);
    int* offsets = (int*)alloc((size_t)NN * 4);
    float* dinv = (float*)alloc((size_t)NN * 4);
    int* bsum = (int*)alloc(128 * 4);
    int2* csr = (int2*)alloc((size_t)EE * 8);
    __half* h16 = (__half*)alloc((size_t)NN * 64 * 2);
    __half* y16 = (__half*)alloc((size_t)NN * 64 * 2);

    const int SCAN_B = (NN + 1023) / 1024;  // 98

    k_zero2<<<(NN + 255) / 256, 256, 0, stream>>>(counts, cursor, NN);
    k_hist<<<EE / 256, 256, 0, stream>>>(ei, counts);
    k_scan_part<<<SCAN_B, 256, 0, stream>>>(counts, bsum, NN);
    k_scan_top<<<1, 64, 0, stream>>>(bsum, SCAN_B);
    k_scan_final<<<SCAN_B, 256, 0, stream>>>(counts, bsum, offsets, dinv, NN);
    k_fill<<<EE / 256, 256, 0, stream>>>(ei, offsets, cursor, dinv, csr);

    // layer 1: K=128, TM=32, fp32 input
    k_gemm<K1, 32, false><<<NN / 32, 256, 0, stream>>>(x, W1, h16);
    k_agg<true, true><<<NN * 64 / 256, 256, 0, stream>>>(h16, csr, offsets, counts, dinv,
                                                         b1, g1, be1, rm1, rv1, y16);
    // layer 2: K=64, TM=64, fp16 input
    k_gemm<HH, 64, true><<<(NN + 63) / 64, 256, 0, stream>>>(y16, W2, h16);
    k_agg<true, true><<<NN * 64 / 256, 256, 0, stream>>>(h16, csr, offsets, counts, dinv,
                                                         b2, g2, be2, rm2, rv2, y16);
    // layer 3: fp32 output to d_out
    k_gemm<HH, 64, true><<<(NN + 63) / 64, 256, 0, stream>>>(y16, W3, h16);
    k_agg<false, false><<<NN * 64 / 256, 256, 0, stream>>>(h16, csr, offsets, counts, dinv,
                                                           b3, b3, b3, b3, b3, out);
}